// Round 1
// baseline (348.948 us; speedup 1.0000x reference)
//
#include <hip/hip_runtime.h>
#include <math.h>

// Problem constants (fixed by reference)
#define M 8192
#define N 16384
#define D 64
#define MTILE 128
#define NTILE 128
#define PCHUNK 4
#define NCHUNK (N / PCHUNK)   // 4096
#define AS 132                // LDS row stride (floats), 132*4B = 528B, 16B-aligned
#define BS 132
#define ZCONST 58.81206612509905f   // 32*log(2*pi)

// d_ws layout (floats)
#define OFF_W   0
#define OFF_R2  16
#define OFF_PM  (16 + N)            // 16400, M*PCHUNK floats
#define OFF_PS  (OFF_PM + M*PCHUNK) // 49168, M*PCHUNK floats

__global__ __launch_bounds__(256) void wsum_kernel(const float* __restrict__ sw,
                                                   float* __restrict__ wdst) {
    __shared__ float red[256];
    float s = 0.f;
    for (int i = threadIdx.x; i < N; i += 256) s += sw[i];
    red[threadIdx.x] = s;
    __syncthreads();
    for (int off = 128; off > 0; off >>= 1) {
        if ((int)threadIdx.x < off) red[threadIdx.x] += red[threadIdx.x + off];
        __syncthreads();
    }
    if (threadIdx.x == 0) wdst[0] = red[0];
}

__global__ __launch_bounds__(256) void r2_kernel(const float* __restrict__ train,
                                                 float* __restrict__ r2h) {
    int n = blockIdx.x * 256 + threadIdx.x;
    if (n >= N) return;
    const float4* p = reinterpret_cast<const float4*>(train + (size_t)n * D);
    float s = 0.f;
#pragma unroll
    for (int i = 0; i < D / 4; ++i) {
        float4 v = p[i];
        s += v.x * v.x + v.y * v.y + v.z * v.z + v.w * v.w;
    }
    r2h[n] = -0.5f * s;   // store -0.5*r2 directly
}

__global__ __launch_bounds__(256) void kde_main_kernel(const float* __restrict__ testX,
                                                       const float* __restrict__ trainX,
                                                       const float* __restrict__ sw,
                                                       const float* __restrict__ r2h,
                                                       float* __restrict__ pm,
                                                       float* __restrict__ ps) {
    __shared__ float As[D * AS];   // As[k][m], 8448 floats
    __shared__ float Bs[D * BS];   // Bs[k][n], 8448 floats
    __shared__ float Ws[NTILE];    // raw weights of current tile
    __shared__ float Rs[NTILE];    // -0.5*r2 of current tile

    const int tid = threadIdx.x;
    const int tx = tid & 15;       // train-col group
    const int ty = tid >> 4;       // test-row group
    const int m0 = blockIdx.x * MTILE;
    const int chunk = blockIdx.y;
    const int c0 = chunk * NCHUNK;

    // ---- stage A tile (once per block): As[k][m] = testX[m0+m][k] ----
    for (int c = tid; c < MTILE * (D / 4); c += 256) {   // 2048 float4 chunks
        int row = c & (MTILE - 1);
        int kg = c >> 7;   // c / 128
        float4 v = *reinterpret_cast<const float4*>(&testX[(size_t)(m0 + row) * D + kg * 4]);
        As[(4 * kg + 0) * AS + row] = v.x;
        As[(4 * kg + 1) * AS + row] = v.y;
        As[(4 * kg + 2) * AS + row] = v.z;
        As[(4 * kg + 3) * AS + row] = v.w;
    }
    __syncthreads();

    // ---- per-thread: -0.5 * t2 for my 8 rows ----
    float au[8];
#pragma unroll
    for (int i = 0; i < 8; ++i) {
        float t = 0.f;
        for (int k = 0; k < D; ++k) {
            float v = As[k * AS + ty * 8 + i];
            t = fmaf(v, v, t);
        }
        au[i] = -0.5f * t;
    }

    // online LSE state (in u-space: u = dot - 0.5*t2 - 0.5*r2)
    float mrun[8], srun[8];
#pragma unroll
    for (int i = 0; i < 8; ++i) { mrun[i] = -INFINITY; srun[i] = 0.f; }

    for (int t = 0; t < NCHUNK / NTILE; ++t) {   // 32 tiles
        const int c0t = c0 + t * NTILE;
        __syncthreads();   // prior tile's consumers done before restage
        // ---- stage B tile: Bs[k][n] = trainX[c0t+n][k] ----
        for (int c = tid; c < NTILE * (D / 4); c += 256) {
            int col = c & (NTILE - 1);
            int kg = c >> 7;
            float4 v = *reinterpret_cast<const float4*>(&trainX[(size_t)(c0t + col) * D + kg * 4]);
            Bs[(4 * kg + 0) * BS + col] = v.x;
            Bs[(4 * kg + 1) * BS + col] = v.y;
            Bs[(4 * kg + 2) * BS + col] = v.z;
            Bs[(4 * kg + 3) * BS + col] = v.w;
        }
        if (tid < NTILE) {
            Ws[tid] = sw[c0t + tid];
            Rs[tid] = r2h[c0t + tid];
        }
        __syncthreads();

        // ---- 8x8 register-tiled dot products over K=64 ----
        float acc[8][8];
#pragma unroll
        for (int i = 0; i < 8; ++i)
#pragma unroll
            for (int j = 0; j < 8; ++j) acc[i][j] = 0.f;

#pragma unroll 4
        for (int k = 0; k < D; ++k) {
            float4 a0 = *reinterpret_cast<const float4*>(&As[k * AS + ty * 8]);
            float4 a1 = *reinterpret_cast<const float4*>(&As[k * AS + ty * 8 + 4]);
            float4 b0 = *reinterpret_cast<const float4*>(&Bs[k * BS + tx * 8]);
            float4 b1 = *reinterpret_cast<const float4*>(&Bs[k * BS + tx * 8 + 4]);
            float a[8] = {a0.x, a0.y, a0.z, a0.w, a1.x, a1.y, a1.z, a1.w};
            float b[8] = {b0.x, b0.y, b0.z, b0.w, b1.x, b1.y, b1.z, b1.w};
#pragma unroll
            for (int i = 0; i < 8; ++i)
#pragma unroll
                for (int j = 0; j < 8; ++j)
                    acc[i][j] = fmaf(a[i], b[j], acc[i][j]);
        }

        // ---- online weighted LSE update for my 8x8 block ----
#pragma unroll
        for (int i = 0; i < 8; ++i) {
            float u[8];
            float lm = -INFINITY;
#pragma unroll
            for (int j = 0; j < 8; ++j) {
                u[j] = acc[i][j] + au[i] + Rs[tx * 8 + j];
                lm = fmaxf(lm, u[j]);
            }
            float nm = fmaxf(mrun[i], lm);
            float sl = 0.f;
#pragma unroll
            for (int j = 0; j < 8; ++j)
                sl = fmaf(__expf(u[j] - nm), Ws[tx * 8 + j], sl);
            srun[i] = srun[i] * __expf(mrun[i] - nm) + sl;
            mrun[i] = nm;
        }
    }

    // ---- cross-tx merge via LDS (reuse As storage) ----
    __syncthreads();
    float* redm = As;          // [128][16]
    float* reds = As + MTILE * 16;
#pragma unroll
    for (int i = 0; i < 8; ++i) {
        redm[(ty * 8 + i) * 16 + tx] = mrun[i];
        reds[(ty * 8 + i) * 16 + tx] = srun[i];
    }
    __syncthreads();
    if (tid < MTILE) {
        float mg = -INFINITY;
#pragma unroll
        for (int t = 0; t < 16; ++t) mg = fmaxf(mg, redm[tid * 16 + t]);
        float sg = 0.f;
#pragma unroll
        for (int t = 0; t < 16; ++t)
            sg += reds[tid * 16 + t] * __expf(redm[tid * 16 + t] - mg);
        pm[(size_t)(m0 + tid) * PCHUNK + chunk] = mg;
        ps[(size_t)(m0 + tid) * PCHUNK + chunk] = sg;
    }
}

__global__ __launch_bounds__(256) void merge_kernel(const float* __restrict__ pm,
                                                    const float* __restrict__ ps,
                                                    const float* __restrict__ wsum,
                                                    float* __restrict__ out) {
    int r = blockIdx.x * 256 + threadIdx.x;
    if (r >= M) return;
    float mg = -INFINITY;
#pragma unroll
    for (int p = 0; p < PCHUNK; ++p) mg = fmaxf(mg, pm[(size_t)r * PCHUNK + p]);
    float sg = 0.f;
#pragma unroll
    for (int p = 0; p < PCHUNK; ++p)
        sg += ps[(size_t)r * PCHUNK + p] * __expf(pm[(size_t)r * PCHUNK + p] - mg);
    float W = wsum[0];
    out[r] = mg - ZCONST + logf(sg / W + 1e-20f);
}

extern "C" void kernel_launch(void* const* d_in, const int* in_sizes, int n_in,
                              void* d_out, int out_size, void* d_ws, size_t ws_size,
                              hipStream_t stream) {
    const float* testX  = (const float*)d_in[0];   // [8192, 64]
    const float* trainX = (const float*)d_in[1];   // [16384, 64]
    const float* sw     = (const float*)d_in[2];   // [16384]
    float* out = (float*)d_out;                    // [8192]
    float* ws = (float*)d_ws;

    float* wdst = ws + OFF_W;
    float* r2h  = ws + OFF_R2;
    float* pm   = ws + OFF_PM;
    float* ps   = ws + OFF_PS;

    wsum_kernel<<<1, 256, 0, stream>>>(sw, wdst);
    r2_kernel<<<N / 256, 256, 0, stream>>>(trainX, r2h);
    kde_main_kernel<<<dim3(M / MTILE, PCHUNK), 256, 0, stream>>>(testX, trainX, sw, r2h, pm, ps);
    merge_kernel<<<M / 256, 256, 0, stream>>>(pm, ps, wdst, out);
}

// Round 2
// 108.634 us; speedup vs baseline: 3.2121x; 3.2121x over previous
//
#include <hip/hip_runtime.h>
#include <hip/hip_bf16.h>
#include <math.h>

// ---------------- problem constants ----------------
#define M 8192
#define N 16384
#define D 64
#define ZC 58.81206612509905f        // 32*log(2*pi), h=1
#define B0 24.0f                     // exp2-domain bias (underflow headroom)
#define LOG2E 1.4426950408889634f
#define HL2E 0.7213475204444817f     // 0.5*log2(e)
#define LN2 0.6931471805599453f

// ---------------- fast path (bf16 MFMA) ----------------
#define PCH 16
#define NCHK (N / PCH)               // 1024 train cols per block

typedef short v8bf __attribute__((ext_vector_type(8)));   // 8 bf16 in 4 VGPRs
typedef float v16f __attribute__((ext_vector_type(16)));

// ws byte offsets (fast path)
#define B_W    0
#define B_AU2  64                       // 8192 f32
#define B_LW2  32832                    // 16384 f32
#define B_PART 98368                    // 8192*16 f32
#define B_TB   622656                   // 8192*64 bf16
#define B_TR   1671232                  // 16384*64 bf16
#define WS_NEED 3768384

__global__ __launch_bounds__(256) void wsum_kernel(const float* __restrict__ sw,
                                                   float* __restrict__ wdst) {
    __shared__ float red[256];
    float s = 0.f;
    for (int i = threadIdx.x; i < N; i += 256) s += sw[i];
    red[threadIdx.x] = s;
    __syncthreads();
    for (int off = 128; off > 0; off >>= 1) {
        if ((int)threadIdx.x < off) red[threadIdx.x] += red[threadIdx.x + off];
        __syncthreads();
    }
    if (threadIdx.x == 0) wdst[0] = red[0];
}

// test prep: bf16(log2e * x), au2[m] = -0.5*log2e*t2 (exact fp32 t2)
__global__ __launch_bounds__(256) void prep_test(const float* __restrict__ X,
                                                 __hip_bfloat16* __restrict__ xb,
                                                 float* __restrict__ au2) {
    const int tid = threadIdx.x;
    const int row = blockIdx.x * 32 + (tid >> 3);
    const int e = tid & 7;
    const float4* p = reinterpret_cast<const float4*>(X + (size_t)row * D + e * 8);
    float4 v0 = p[0], v1 = p[1];
    float t2 = v0.x * v0.x + v0.y * v0.y + v0.z * v0.z + v0.w * v0.w
             + v1.x * v1.x + v1.y * v1.y + v1.z * v1.z + v1.w * v1.w;
    t2 += __shfl_xor(t2, 1, 64);
    t2 += __shfl_xor(t2, 2, 64);
    t2 += __shfl_xor(t2, 4, 64);
    if (e == 0) au2[row] = -HL2E * t2;
    union { __hip_bfloat16 h[8]; uint4 u; } cv;
    cv.h[0] = __float2bfloat16(v0.x * LOG2E);
    cv.h[1] = __float2bfloat16(v0.y * LOG2E);
    cv.h[2] = __float2bfloat16(v0.z * LOG2E);
    cv.h[3] = __float2bfloat16(v0.w * LOG2E);
    cv.h[4] = __float2bfloat16(v1.x * LOG2E);
    cv.h[5] = __float2bfloat16(v1.y * LOG2E);
    cv.h[6] = __float2bfloat16(v1.z * LOG2E);
    cv.h[7] = __float2bfloat16(v1.w * LOG2E);
    *reinterpret_cast<uint4*>(xb + (size_t)row * D + e * 8) = cv.u;
}

// train prep: bf16(y), lw2[n] = log2(w) - 0.5*log2e*r2 + B0
__global__ __launch_bounds__(256) void prep_train(const float* __restrict__ Y,
                                                  const float* __restrict__ sw,
                                                  __hip_bfloat16* __restrict__ yb,
                                                  float* __restrict__ lw2) {
    const int tid = threadIdx.x;
    const int row = blockIdx.x * 32 + (tid >> 3);
    const int e = tid & 7;
    const float4* p = reinterpret_cast<const float4*>(Y + (size_t)row * D + e * 8);
    float4 v0 = p[0], v1 = p[1];
    float r2 = v0.x * v0.x + v0.y * v0.y + v0.z * v0.z + v0.w * v0.w
             + v1.x * v1.x + v1.y * v1.y + v1.z * v1.z + v1.w * v1.w;
    r2 += __shfl_xor(r2, 1, 64);
    r2 += __shfl_xor(r2, 2, 64);
    r2 += __shfl_xor(r2, 4, 64);
    if (e == 0) lw2[row] = __builtin_amdgcn_logf(sw[row]) - HL2E * r2 + B0;
    union { __hip_bfloat16 h[8]; uint4 u; } cv;
    cv.h[0] = __float2bfloat16(v0.x);
    cv.h[1] = __float2bfloat16(v0.y);
    cv.h[2] = __float2bfloat16(v0.z);
    cv.h[3] = __float2bfloat16(v0.w);
    cv.h[4] = __float2bfloat16(v1.x);
    cv.h[5] = __float2bfloat16(v1.y);
    cv.h[6] = __float2bfloat16(v1.z);
    cv.h[7] = __float2bfloat16(v1.w);
    *reinterpret_cast<uint4*>(yb + (size_t)row * D + e * 8) = cv.u;
}

// main: 128 test rows x 1024 train cols per block; MFMA 32x32x16 bf16;
// acc initialized with lw2 (bias folded into MFMA C operand); epilogue
// is exp2 + add only (no max needed: u <= 0, B0 guards underflow).
__global__ __launch_bounds__(256, 4) void gk_main(const __hip_bfloat16* __restrict__ ta,
                                                  const __hip_bfloat16* __restrict__ tr,
                                                  const float* __restrict__ lw2,
                                                  float* __restrict__ part) {
    __shared__ __align__(16) char smem[33280];   // As 16K | Bs 16K | Lw 512B
    const int tid = threadIdx.x;
    const int w = tid >> 6;
    const int lane = tid & 63;
    const int c = lane & 31;
    const int h = lane >> 5;
    const int rl = lane >> 3;      // 0..7 row within staging group
    const int kb = lane & 7;       // 16B k-chunk index
    const int m0 = blockIdx.x * 128;
    const int chunk = blockIdx.y;
    const int n0 = chunk * NCHK;

    // ---- stage A tile (once): LDS[kb][m^kb] (xor-swizzle kills write conflicts)
#pragma unroll
    for (int i = 0; i < 4; ++i) {
        int rr = w * 32 + i * 8 + rl;
        uint4 v = *reinterpret_cast<const uint4*>(ta + (size_t)(m0 + rr) * D + kb * 8);
        *reinterpret_cast<uint4*>(smem + kb * 2048 + ((rr ^ kb) * 16)) = v;
    }
    __syncthreads();

    // A fragments resident for the whole sweep: A[m=lane&31][k=h*8+j], K-step t
    v8bf af[4];
#pragma unroll
    for (int t = 0; t < 4; ++t) {
        int kk = 2 * t + h;
        af[t] = *reinterpret_cast<const v8bf*>(smem + kk * 2048 + (((w * 32 + c) ^ kk) * 16));
    }

    float srun[16];
#pragma unroll
    for (int r = 0; r < 16; ++r) srun[r] = 0.f;

    char* Bs = smem + 16384;
    float* Lw = reinterpret_cast<float*>(smem + 32768);

    for (int tile = 0; tile < NCHK / 128; ++tile) {
        __syncthreads();
        const int nt0 = n0 + tile * 128;
#pragma unroll
        for (int i = 0; i < 4; ++i) {
            int rr = w * 32 + i * 8 + rl;
            uint4 v = *reinterpret_cast<const uint4*>(tr + (size_t)(nt0 + rr) * D + kb * 8);
            *reinterpret_cast<uint4*>(Bs + kb * 2048 + ((rr ^ kb) * 16)) = v;
        }
        if (tid < 128) Lw[tid] = lw2[nt0 + tid];
        __syncthreads();

#pragma unroll
        for (int s = 0; s < 4; ++s) {
            float lwv = Lw[s * 32 + c];
            v16f acc;
#pragma unroll
            for (int r = 0; r < 16; ++r) acc[r] = lwv;   // bias = C operand
#pragma unroll
            for (int t = 0; t < 4; ++t) {
                int kk = 2 * t + h;
                v8bf bf = *reinterpret_cast<const v8bf*>(Bs + kk * 2048 + (((s * 32 + c) ^ kk) * 16));
                acc = __builtin_amdgcn_mfma_f32_32x32x16_bf16(af[t], bf, acc, 0, 0, 0);
            }
#pragma unroll
            for (int r = 0; r < 16; ++r)
                srun[r] += __builtin_amdgcn_exp2f(acc[r]);
        }
    }

    // ---- cross-lane row sum (cols live across 32 lanes) ----
    __syncthreads();
    float* red = reinterpret_cast<float*>(smem);   // 128 x 33 f32 = 16896 B
#pragma unroll
    for (int r = 0; r < 16; ++r) {
        int rowl = (r & 3) + 8 * (r >> 2) + 4 * h;
        red[(w * 32 + rowl) * 33 + c] = srun[r];
    }
    __syncthreads();
    if (tid < 128) {
        float G = 0.f;
#pragma unroll
        for (int c2 = 0; c2 < 32; ++c2) G += red[tid * 33 + c2];
        part[(size_t)(m0 + tid) * PCH + chunk] = G;
    }
}

__global__ __launch_bounds__(256) void gk_merge(const float* __restrict__ part,
                                                const float* __restrict__ au2,
                                                const float* __restrict__ wsf,
                                                float* __restrict__ out) {
    const int r = blockIdx.x * 256 + threadIdx.x;
    float G = 0.f;
#pragma unroll
    for (int p = 0; p < PCH; ++p) G += part[(size_t)r * PCH + p];
    float l2W = __builtin_amdgcn_logf(wsf[0]);
    out[r] = LN2 * (au2[r] + __builtin_amdgcn_logf(fmaxf(G, 1e-30f)) - B0 - l2W) - ZC;
}

// ---------------- fallback fp32 path (round-1, used only if ws too small) ----------------
#define FMT 128
#define FNT 128
#define FPC 4
#define FNC (N / FPC)
#define FAS 132
#define F_OFF_W   0
#define F_OFF_R2  16
#define F_OFF_PM  (16 + N)
#define F_OFF_PS  (F_OFF_PM + M * FPC)

__global__ __launch_bounds__(256) void f_r2_kernel(const float* __restrict__ train,
                                                   float* __restrict__ r2h) {
    int n = blockIdx.x * 256 + threadIdx.x;
    if (n >= N) return;
    const float4* p = reinterpret_cast<const float4*>(train + (size_t)n * D);
    float s = 0.f;
#pragma unroll
    for (int i = 0; i < D / 4; ++i) {
        float4 v = p[i];
        s += v.x * v.x + v.y * v.y + v.z * v.z + v.w * v.w;
    }
    r2h[n] = -0.5f * s;
}

__global__ __launch_bounds__(256) void f_main_kernel(const float* __restrict__ testX,
                                                     const float* __restrict__ trainX,
                                                     const float* __restrict__ sw,
                                                     const float* __restrict__ r2h,
                                                     float* __restrict__ pm,
                                                     float* __restrict__ ps) {
    __shared__ float As[D * FAS];
    __shared__ float Bs[D * FAS];
    __shared__ float Ws[FNT];
    __shared__ float Rs[FNT];
    const int tid = threadIdx.x;
    const int tx = tid & 15;
    const int ty = tid >> 4;
    const int m0 = blockIdx.x * FMT;
    const int c0 = blockIdx.y * FNC;
    for (int cc = tid; cc < FMT * (D / 4); cc += 256) {
        int row = cc & (FMT - 1);
        int kg = cc >> 7;
        float4 v = *reinterpret_cast<const float4*>(&testX[(size_t)(m0 + row) * D + kg * 4]);
        As[(4 * kg + 0) * FAS + row] = v.x;
        As[(4 * kg + 1) * FAS + row] = v.y;
        As[(4 * kg + 2) * FAS + row] = v.z;
        As[(4 * kg + 3) * FAS + row] = v.w;
    }
    __syncthreads();
    float au[8];
#pragma unroll
    for (int i = 0; i < 8; ++i) {
        float t = 0.f;
        for (int k = 0; k < D; ++k) {
            float v = As[k * FAS + ty * 8 + i];
            t = fmaf(v, v, t);
        }
        au[i] = -0.5f * t;
    }
    float mrun[8], srun[8];
#pragma unroll
    for (int i = 0; i < 8; ++i) { mrun[i] = -INFINITY; srun[i] = 0.f; }
    for (int t = 0; t < FNC / FNT; ++t) {
        const int c0t = c0 + t * FNT;
        __syncthreads();
        for (int cc = tid; cc < FNT * (D / 4); cc += 256) {
            int col = cc & (FNT - 1);
            int kg = cc >> 7;
            float4 v = *reinterpret_cast<const float4*>(&trainX[(size_t)(c0t + col) * D + kg * 4]);
            Bs[(4 * kg + 0) * FAS + col] = v.x;
            Bs[(4 * kg + 1) * FAS + col] = v.y;
            Bs[(4 * kg + 2) * FAS + col] = v.z;
            Bs[(4 * kg + 3) * FAS + col] = v.w;
        }
        if (tid < FNT) { Ws[tid] = sw[c0t + tid]; Rs[tid] = r2h[c0t + tid]; }
        __syncthreads();
        float acc[8][8];
#pragma unroll
        for (int i = 0; i < 8; ++i)
#pragma unroll
            for (int j = 0; j < 8; ++j) acc[i][j] = 0.f;
#pragma unroll 4
        for (int k = 0; k < D; ++k) {
            float4 a0 = *reinterpret_cast<const float4*>(&As[k * FAS + ty * 8]);
            float4 a1 = *reinterpret_cast<const float4*>(&As[k * FAS + ty * 8 + 4]);
            float4 b0 = *reinterpret_cast<const float4*>(&Bs[k * FAS + tx * 8]);
            float4 b1 = *reinterpret_cast<const float4*>(&Bs[k * FAS + tx * 8 + 4]);
            float a[8] = {a0.x, a0.y, a0.z, a0.w, a1.x, a1.y, a1.z, a1.w};
            float b[8] = {b0.x, b0.y, b0.z, b0.w, b1.x, b1.y, b1.z, b1.w};
#pragma unroll
            for (int i = 0; i < 8; ++i)
#pragma unroll
                for (int j = 0; j < 8; ++j)
                    acc[i][j] = fmaf(a[i], b[j], acc[i][j]);
        }
#pragma unroll
        for (int i = 0; i < 8; ++i) {
            float u[8];
            float lm = -INFINITY;
#pragma unroll
            for (int j = 0; j < 8; ++j) {
                u[j] = acc[i][j] + au[i] + Rs[tx * 8 + j];
                lm = fmaxf(lm, u[j]);
            }
            float nm = fmaxf(mrun[i], lm);
            float sl = 0.f;
#pragma unroll
            for (int j = 0; j < 8; ++j)
                sl = fmaf(__expf(u[j] - nm), Ws[tx * 8 + j], sl);
            srun[i] = srun[i] * __expf(mrun[i] - nm) + sl;
            mrun[i] = nm;
        }
    }
    __syncthreads();
    float* redm = As;
    float* reds = As + FMT * 16;
#pragma unroll
    for (int i = 0; i < 8; ++i) {
        redm[(ty * 8 + i) * 16 + tx] = mrun[i];
        reds[(ty * 8 + i) * 16 + tx] = srun[i];
    }
    __syncthreads();
    if (tid < FMT) {
        float mg = -INFINITY;
#pragma unroll
        for (int t = 0; t < 16; ++t) mg = fmaxf(mg, redm[tid * 16 + t]);
        float sg = 0.f;
#pragma unroll
        for (int t = 0; t < 16; ++t)
            sg += reds[tid * 16 + t] * __expf(redm[tid * 16 + t] - mg);
        pm[(size_t)(m0 + tid) * FPC + blockIdx.y] = mg;
        ps[(size_t)(m0 + tid) * FPC + blockIdx.y] = sg;
    }
}

__global__ __launch_bounds__(256) void f_merge_kernel(const float* __restrict__ pm,
                                                      const float* __restrict__ ps,
                                                      const float* __restrict__ wsum,
                                                      float* __restrict__ out) {
    int r = blockIdx.x * 256 + threadIdx.x;
    if (r >= M) return;
    float mg = -INFINITY;
#pragma unroll
    for (int p = 0; p < FPC; ++p) mg = fmaxf(mg, pm[(size_t)r * FPC + p]);
    float sg = 0.f;
#pragma unroll
    for (int p = 0; p < FPC; ++p)
        sg += ps[(size_t)r * FPC + p] * __expf(pm[(size_t)r * FPC + p] - mg);
    out[r] = mg - ZC + logf(sg / wsum[0] + 1e-20f);
}

extern "C" void kernel_launch(void* const* d_in, const int* in_sizes, int n_in,
                              void* d_out, int out_size, void* d_ws, size_t ws_size,
                              hipStream_t stream) {
    const float* testX  = (const float*)d_in[0];
    const float* trainX = (const float*)d_in[1];
    const float* sw     = (const float*)d_in[2];
    float* out = (float*)d_out;
    char* wsb = (char*)d_ws;
    float* wsf = (float*)d_ws;

    if (ws_size >= (size_t)WS_NEED) {
        float* au2  = (float*)(wsb + B_AU2);
        float* lw2  = (float*)(wsb + B_LW2);
        float* part = (float*)(wsb + B_PART);
        __hip_bfloat16* tb = (__hip_bfloat16*)(wsb + B_TB);
        __hip_bfloat16* rb = (__hip_bfloat16*)(wsb + B_TR);
        wsum_kernel<<<1, 256, 0, stream>>>(sw, wsf);
        prep_test<<<M / 32, 256, 0, stream>>>(testX, tb, au2);
        prep_train<<<N / 32, 256, 0, stream>>>(trainX, sw, rb, lw2);
        gk_main<<<dim3(M / 128, PCH), 256, 0, stream>>>(tb, rb, lw2, part);
        gk_merge<<<M / 256, 256, 0, stream>>>(part, au2, wsf, out);
    } else {
        float* r2h = wsf + F_OFF_R2;
        float* pm  = wsf + F_OFF_PM;
        float* ps  = wsf + F_OFF_PS;
        wsum_kernel<<<1, 256, 0, stream>>>(sw, wsf);
        f_r2_kernel<<<N / 256, 256, 0, stream>>>(trainX, r2h);
        f_main_kernel<<<dim3(M / FMT, FPC), 256, 0, stream>>>(testX, trainX, sw, r2h, pm, ps);
        f_merge_kernel<<<M / 256, 256, 0, stream>>>(pm, ps, wsf, out);
    }
}

// Round 3
// 105.507 us; speedup vs baseline: 3.3073x; 1.0296x over previous
//
#include <hip/hip_runtime.h>
#include <hip/hip_bf16.h>
#include <math.h>

// ---------------- problem constants ----------------
#define M 8192
#define N 16384
#define D 64
#define ZC 58.81206612509905f        // 32*log(2*pi), h=1
#define B0 24.0f                     // exp2-domain bias (headroom; u<=0 keeps exp2 bounded)
#define LOG2E 1.4426950408889634f
#define HL2E 0.7213475204444817f     // 0.5*log2(e)
#define LN2 0.6931471805599453f

#define PCH 16
#define NCHK (N / PCH)               // 1024 train cols per block

typedef short v8bf __attribute__((ext_vector_type(8)));   // 8 bf16 (4 VGPRs)
typedef float v16f __attribute__((ext_vector_type(16)));

// ws layout (bytes)
#define B_AU2  0                     // 8192 f32   (32 KB)
#define B_PART 32768                 // 16*8192 f32 (512 KB), layout [chunk][m]

// Fused kernel: stages raw f32 inputs -> bf16 LDS tiles (converting on the
// fly), computes lw2 = log2(w) - 0.5*log2e*r2 + B0 during staging, runs
// MFMA 32x32x16 bf16 with the bias folded into the C operand, epilogue is
// exp2 + add (no max needed: exponent <= B0 + small, no overflow; far pairs
// underflow to 0 exactly as the reference LSE drops them).
__global__ __launch_bounds__(256, 4) void gk_main(const float* __restrict__ testX,
                                                  const float* __restrict__ trainX,
                                                  const float* __restrict__ sw,
                                                  float* __restrict__ au2,
                                                  float* __restrict__ part) {
    __shared__ __align__(16) char smem[33280];   // As 16K | Bs 16K | Lw 512B
    const int tid = threadIdx.x;
    const int w = tid >> 6;
    const int lane = tid & 63;
    const int c = lane & 31;
    const int h = lane >> 5;
    const int rl = lane >> 3;      // staging row-in-group 0..7
    const int kb = lane & 7;       // staging 16B k-chunk 0..7

    // XCD-aware mapping: xcd (bid&7) owns chunks {2x, 2x+1} -> each XCD's L2
    // caches only 2*1024 train rows (512 KB f32) + A (2 MB) = fits 4 MB L2.
    const int bid = blockIdx.x;
    const int xcd = bid & 7;
    const int j = bid >> 3;
    const int chunk = xcd * 2 + (j & 1);
    const int m0 = (j >> 1) * 128;
    const int n0 = chunk * NCHK;

    // ---- stage A (f32 -> bf16(log2e*x)); xor-swizzled LDS; au2 from chunk 0
#pragma unroll
    for (int i = 0; i < 4; ++i) {
        int rr = w * 32 + i * 8 + rl;
        const float4* p = reinterpret_cast<const float4*>(testX + (size_t)(m0 + rr) * D + kb * 8);
        float4 v0 = p[0], v1 = p[1];
        float t2 = v0.x * v0.x + v0.y * v0.y + v0.z * v0.z + v0.w * v0.w
                 + v1.x * v1.x + v1.y * v1.y + v1.z * v1.z + v1.w * v1.w;
        t2 += __shfl_xor(t2, 1, 64);
        t2 += __shfl_xor(t2, 2, 64);
        t2 += __shfl_xor(t2, 4, 64);
        if (chunk == 0 && kb == 0) au2[m0 + rr] = -HL2E * t2;
        union { __hip_bfloat16 hx[8]; uint4 u; } cv;
        cv.hx[0] = __float2bfloat16(v0.x * LOG2E);
        cv.hx[1] = __float2bfloat16(v0.y * LOG2E);
        cv.hx[2] = __float2bfloat16(v0.z * LOG2E);
        cv.hx[3] = __float2bfloat16(v0.w * LOG2E);
        cv.hx[4] = __float2bfloat16(v1.x * LOG2E);
        cv.hx[5] = __float2bfloat16(v1.y * LOG2E);
        cv.hx[6] = __float2bfloat16(v1.z * LOG2E);
        cv.hx[7] = __float2bfloat16(v1.w * LOG2E);
        *reinterpret_cast<uint4*>(smem + kb * 2048 + ((rr ^ kb) * 16)) = cv.u;
    }
    __syncthreads();

    // A fragments resident for the whole sweep: wave w covers rows w*32+c
    v8bf af[4];
#pragma unroll
    for (int t = 0; t < 4; ++t) {
        int kk = 2 * t + h;
        af[t] = *reinterpret_cast<const v8bf*>(smem + kk * 2048 + (((w * 32 + c) ^ kk) * 16));
    }

    float srun[16];
#pragma unroll
    for (int r = 0; r < 16; ++r) srun[r] = 0.f;

    char* Bs = smem + 16384;
    float* Lw = reinterpret_cast<float*>(smem + 32768);

    for (int tile = 0; tile < NCHK / 128; ++tile) {
        __syncthreads();
        const int nt0 = n0 + tile * 128;
        // ---- stage B (f32 -> bf16) + lw2 on the fly ----
#pragma unroll
        for (int i = 0; i < 4; ++i) {
            int rr = w * 32 + i * 8 + rl;
            float swv = sw[nt0 + rr];   // same addr across the 8-lane group: broadcast
            const float4* p = reinterpret_cast<const float4*>(trainX + (size_t)(nt0 + rr) * D + kb * 8);
            float4 v0 = p[0], v1 = p[1];
            float r2 = v0.x * v0.x + v0.y * v0.y + v0.z * v0.z + v0.w * v0.w
                     + v1.x * v1.x + v1.y * v1.y + v1.z * v1.z + v1.w * v1.w;
            r2 += __shfl_xor(r2, 1, 64);
            r2 += __shfl_xor(r2, 2, 64);
            r2 += __shfl_xor(r2, 4, 64);
            if (kb == 0) Lw[rr] = __builtin_amdgcn_logf(swv) - HL2E * r2 + B0;  // log2 domain
            union { __hip_bfloat16 hx[8]; uint4 u; } cv;
            cv.hx[0] = __float2bfloat16(v0.x);
            cv.hx[1] = __float2bfloat16(v0.y);
            cv.hx[2] = __float2bfloat16(v0.z);
            cv.hx[3] = __float2bfloat16(v0.w);
            cv.hx[4] = __float2bfloat16(v1.x);
            cv.hx[5] = __float2bfloat16(v1.y);
            cv.hx[6] = __float2bfloat16(v1.z);
            cv.hx[7] = __float2bfloat16(v1.w);
            *reinterpret_cast<uint4*>(Bs + kb * 2048 + ((rr ^ kb) * 16)) = cv.u;
        }
        __syncthreads();

#pragma unroll
        for (int s = 0; s < 4; ++s) {
            float lwv = Lw[s * 32 + c];
            v16f acc;
#pragma unroll
            for (int r = 0; r < 16; ++r) acc[r] = lwv;   // bias = MFMA C operand
#pragma unroll
            for (int t = 0; t < 4; ++t) {
                int kk = 2 * t + h;
                v8bf bf = *reinterpret_cast<const v8bf*>(Bs + kk * 2048 + (((s * 32 + c) ^ kk) * 16));
                acc = __builtin_amdgcn_mfma_f32_32x32x16_bf16(af[t], bf, acc, 0, 0, 0);
            }
#pragma unroll
            for (int r = 0; r < 16; ++r)
                srun[r] += __builtin_amdgcn_exp2f(acc[r]);
        }
    }

    // ---- cross-lane row sum (cols live across 32 lanes) ----
    __syncthreads();
    float* red = reinterpret_cast<float*>(smem);   // 128 x 33 f32
#pragma unroll
    for (int r = 0; r < 16; ++r) {
        int rowl = (r & 3) + 8 * (r >> 2) + 4 * h;
        red[(w * 32 + rowl) * 33 + c] = srun[r];
    }
    __syncthreads();
    if (tid < 128) {
        float G = 0.f;
#pragma unroll
        for (int c2 = 0; c2 < 32; ++c2) G += red[tid * 33 + c2];
        part[(size_t)chunk * M + m0 + tid] = G;   // [chunk][m] -> coalesced merge
    }
}

__global__ __launch_bounds__(256) void gk_merge(const float* __restrict__ part,
                                                const float* __restrict__ au2,
                                                const float* __restrict__ sw,
                                                float* __restrict__ out) {
    __shared__ float red[256];
    const int tid = threadIdx.x;
    // W = sum(sw), recomputed per block (64 KB, L2-resident, fully parallel)
    float s = 0.f;
    const float4* p4 = reinterpret_cast<const float4*>(sw);
    for (int i = tid; i < N / 4; i += 256) {
        float4 v = p4[i];
        s += v.x + v.y + v.z + v.w;
    }
    red[tid] = s;
    __syncthreads();
    for (int off = 128; off > 0; off >>= 1) {
        if (tid < off) red[tid] += red[tid + off];
        __syncthreads();
    }
    const float W = red[0];

    const int r = blockIdx.x * 256 + tid;
    float G = 0.f;
#pragma unroll
    for (int p = 0; p < PCH; ++p) G += part[(size_t)p * M + r];
    out[r] = LN2 * (au2[r] + __builtin_amdgcn_logf(fmaxf(G, 1e-30f)) - B0
                   - __builtin_amdgcn_logf(W)) - ZC;
}

extern "C" void kernel_launch(void* const* d_in, const int* in_sizes, int n_in,
                              void* d_out, int out_size, void* d_ws, size_t ws_size,
                              hipStream_t stream) {
    const float* testX  = (const float*)d_in[0];   // [8192, 64]
    const float* trainX = (const float*)d_in[1];   // [16384, 64]
    const float* sw     = (const float*)d_in[2];   // [16384]
    float* out = (float*)d_out;                    // [8192]
    char* wsb = (char*)d_ws;

    float* au2  = (float*)(wsb + B_AU2);
    float* part = (float*)(wsb + B_PART);

    gk_main<<<(M / 128) * PCH, 256, 0, stream>>>(testX, trainX, sw, au2, part);
    gk_merge<<<M / 256, 256, 0, stream>>>(part, au2, sw, out);
}